// Round 2
// baseline (634.848 us; speedup 1.0000x reference)
//
#include <hip/hip_runtime.h>
#include <hip/hip_bf16.h>

// MHA layer. B=4, S=2048, HID=512, H=8, HD=64. Inputs fp32 (per reference),
// mask int32, output fp32. Internal compute bf16 MFMA (threshold 1.77e-3
// accommodates bf16 internal rounding; estimated absmax ~1e-4).
//
// Pipeline:
//   K1 qkv_gemm : Q/K/V = x @ W^T + b   -> ws (Q,K as [B,H,S,64] bf16, V as [B,H,64,S] bf16)
//   K2 attn     : flash attention       -> ws AO [B,S,512] bf16
//   K3 out_gemm : AO @ Wo^T + bo        -> d_out [B,S,512] fp32
//
// MFMA 16x16x32_bf16 layouts (HW-verified per guide m89/m91/m120):
//   A-operand: A[m=lane&15][k=quad*8+j]
//   B-operand: holds B'[n=lane&15][k=quad*8+j], computes sum_k A[m][k]*B'[n][k]
//   C/D:       col=lane&15, row=quad*4+reg

typedef __bf16 v8bf __attribute__((ext_vector_type(8)));
typedef float  v4f  __attribute__((ext_vector_type(4)));

#define MFMA16(a, b, c) __builtin_amdgcn_mfma_f32_16x16x32_bf16((a), (b), (c), 0, 0, 0)

// Load 8 contiguous fp32, convert to bf16 fragment (k-contiguous).
__device__ inline v8bf load8f_bf(const float* __restrict__ p) {
    const v4f a = *(const v4f*)p;
    const v4f b = *(const v4f*)(p + 4);
    v8bf r;
    r[0] = (__bf16)a[0]; r[1] = (__bf16)a[1]; r[2] = (__bf16)a[2]; r[3] = (__bf16)a[3];
    r[4] = (__bf16)b[0]; r[5] = (__bf16)b[1]; r[6] = (__bf16)b[2]; r[7] = (__bf16)b[3];
    return r;
}

// ---------------------------------------------------------------------------
// K1: QKV projection. grid (128, 8, 3), block 256 (4 waves, 2x2 of 32x32).
// x:[8192,512] fp32, W:[512,512] fp32 (row-major, y = x@W^T), K-loop 512/32.
// ---------------------------------------------------------------------------
__global__ __launch_bounds__(256) void qkv_gemm(
    const float* __restrict__ xq, const float* __restrict__ xk, const float* __restrict__ xv,
    const float* __restrict__ Wq, const float* __restrict__ Wk, const float* __restrict__ Wv,
    const float* __restrict__ bq, const float* __restrict__ bk, const float* __restrict__ bv,
    __bf16* __restrict__ Qo, __bf16* __restrict__ Ko, __bf16* __restrict__ VTo)
{
    const int z = blockIdx.z;
    const float* x    = (z == 0) ? xq : (z == 1) ? xk : xv;
    const float* W    = (z == 0) ? Wq : (z == 1) ? Wk : Wv;
    const float* bias = (z == 0) ? bq : (z == 1) ? bk : bv;

    const int tid  = threadIdx.x;
    const int wave = tid >> 6, lane = tid & 63;
    const int quad = lane >> 4, r = lane & 15;
    const int row0 = blockIdx.x * 64 + (wave >> 1) * 32;  // M
    const int col0 = blockIdx.y * 64 + (wave & 1) * 32;   // N

    v4f acc[2][2] = {};

    for (int kk = 0; kk < 512; kk += 32) {
        v8bf a0 = load8f_bf(x + (size_t)(row0 +      r) * 512 + kk + quad * 8);
        v8bf a1 = load8f_bf(x + (size_t)(row0 + 16 + r) * 512 + kk + quad * 8);
        v8bf b0 = load8f_bf(W + (size_t)(col0 +      r) * 512 + kk + quad * 8);
        v8bf b1 = load8f_bf(W + (size_t)(col0 + 16 + r) * 512 + kk + quad * 8);
        acc[0][0] = MFMA16(a0, b0, acc[0][0]);
        acc[0][1] = MFMA16(a0, b1, acc[0][1]);
        acc[1][0] = MFMA16(a1, b0, acc[1][0]);
        acc[1][1] = MFMA16(a1, b1, acc[1][1]);
    }

    for (int ni = 0; ni < 2; ni++) {
        const int n  = col0 + ni * 16 + r;   // output feature
        const float bv_ = bias[n];
        const int h = n >> 6, hd = n & 63;
        for (int mi = 0; mi < 2; mi++) {
            for (int i = 0; i < 4; i++) {
                const int m = row0 + mi * 16 + quad * 4 + i;
                const int b = m >> 11, s = m & 2047;
                const float v = acc[mi][ni][i] + bv_;
                if (z == 2) {
                    // V transposed: VT[bh*64 + hd][s]
                    VTo[((size_t)((b * 8 + h) * 64 + hd)) * 2048 + s] = (__bf16)v;
                } else {
                    __bf16* dst = (z == 0) ? Qo : Ko;
                    dst[((size_t)((b * 8 + h) * 2048 + s)) * 64 + hd] = (__bf16)v;
                }
            }
        }
    }
}

// ---------------------------------------------------------------------------
// K2: flash attention. grid (32, 32), block 256. Wave w: 16 queries.
// K-tiles of 64 keys, online softmax, P transposed via LDS.
// ---------------------------------------------------------------------------
__global__ __launch_bounds__(256) void attn(
    const __bf16* __restrict__ Q, const __bf16* __restrict__ K,
    const __bf16* __restrict__ VT, const int* __restrict__ mask,
    __bf16* __restrict__ AO)
{
    const int bh = blockIdx.y;           // b*8 + h
    const int b  = bh >> 3, h = bh & 7;
    const int tid  = threadIdx.x;
    const int wave = tid >> 6, lane = tid & 63;
    const int quad = lane >> 4, r = lane & 15;
    const int q0 = blockIdx.x * 64 + wave * 16;

    const __bf16* Qb = Q  + (size_t)bh * 2048 * 64;
    const __bf16* Kb = K  + (size_t)bh * 2048 * 64;
    const __bf16* Vb = VT + (size_t)bh * 64 * 2048;
    const int*    mb = mask + (size_t)b * 2048;

    // Q fragments resident (A-operand): rows q0+r, two k-halves of HD=64
    v8bf qf0 = *(const v8bf*)(Qb + (size_t)(q0 + r) * 64 +      quad * 8);
    v8bf qf1 = *(const v8bf*)(Qb + (size_t)(q0 + r) * 64 + 32 + quad * 8);

    float m_i[4], l_i[4];
    v4f o[4] = {};                       // O over 4 hd-col tiles
    for (int i = 0; i < 4; i++) { m_i[i] = -1e30f; l_i[i] = 0.f; }

    // P transpose staging: per-wave 16x64, row padded to 88 elems (176 B):
    // 16B-aligned ds_read_b128; only 2-way bank aliasing (free).
    __shared__ __bf16 Pls[4][16][88];

    for (int k0 = 0; k0 < 2048; k0 += 64) {
        // ---- scores S[16q][64k] as 4 col-tiles
        v4f sa[4] = {};
        for (int t = 0; t < 4; t++) {
            const __bf16* Kt = Kb + (size_t)(k0 + t * 16 + r) * 64;
            v8bf kf0 = *(const v8bf*)(Kt +      quad * 8);
            v8bf kf1 = *(const v8bf*)(Kt + 32 + quad * 8);
            sa[t] = MFMA16(qf0, kf0, sa[t]);
            sa[t] = MFMA16(qf1, kf1, sa[t]);
        }
        // ---- scale + mask (E = QK/8; masked -> -1e10, like ref)
        for (int t = 0; t < 4; t++) {
            const bool keep = (mb[k0 + t * 16 + r] != 0);
            for (int i = 0; i < 4; i++) {
                float s = sa[t][i] * 0.125f;
                sa[t][i] = keep ? s : -1e10f;
            }
        }
        // ---- online softmax per q-row (row fixed within a 16-lane group)
        float p[4][4], alpha[4];
        for (int i = 0; i < 4; i++) {
            float mx = fmaxf(fmaxf(sa[0][i], sa[1][i]), fmaxf(sa[2][i], sa[3][i]));
            for (int d = 1; d < 16; d <<= 1) mx = fmaxf(mx, __shfl_xor(mx, d));
            const float mnew = fmaxf(m_i[i], mx);
            const float al = __expf(m_i[i] - mnew);   // first tile: exp(-1e30)=0
            float sum = 0.f;
            for (int t = 0; t < 4; t++) {
                const float pv = __expf(sa[t][i] - mnew);
                p[t][i] = pv;
                sum += pv;
            }
            for (int d = 1; d < 16; d <<= 1) sum += __shfl_xor(sum, d);
            l_i[i] = l_i[i] * al + sum;
            m_i[i] = mnew;
            alpha[i] = al;
        }
        for (int t2 = 0; t2 < 4; t2++)
            for (int i = 0; i < 4; i++) o[t2][i] *= alpha[i];

        // ---- P: C-layout -> A-layout via LDS (barriers as ordering insurance)
        __syncthreads();
        for (int t = 0; t < 4; t++)
            for (int i = 0; i < 4; i++)
                Pls[wave][quad * 4 + i][t * 16 + r] = (__bf16)p[t][i];
        __syncthreads();
        v8bf pa0 = *(const v8bf*)&Pls[wave][r][     quad * 8];
        v8bf pa1 = *(const v8bf*)&Pls[wave][r][32 + quad * 8];

        // ---- O += P @ V  (V from VT: 16B vector loads along keys)
        for (int t2 = 0; t2 < 4; t2++) {
            const __bf16* Vt = Vb + (size_t)(t2 * 16 + r) * 2048 + k0;
            v8bf vf0 = *(const v8bf*)(Vt +      quad * 8);
            v8bf vf1 = *(const v8bf*)(Vt + 32 + quad * 8);
            o[t2] = MFMA16(pa0, vf0, o[t2]);
            o[t2] = MFMA16(pa1, vf1, o[t2]);
        }
    }

    // ---- epilogue: O /= l, store AO[b][s][h*64+hd]
    for (int t2 = 0; t2 < 4; t2++) {
        const int hd = t2 * 16 + r;
        for (int i = 0; i < 4; i++) {
            const int s = q0 + quad * 4 + i;
            const float val = o[t2][i] / l_i[i];
            AO[((size_t)b * 2048 + s) * 512 + h * 64 + hd] = (__bf16)val;
        }
    }
}

// ---------------------------------------------------------------------------
// K3: output projection. grid (128, 8), block 256. AO bf16 @ Wo^T fp32 -> fp32.
// ---------------------------------------------------------------------------
__global__ __launch_bounds__(256) void out_gemm(
    const __bf16* __restrict__ x, const float* __restrict__ W,
    const float* __restrict__ bias, float* __restrict__ y)
{
    const int tid  = threadIdx.x;
    const int wave = tid >> 6, lane = tid & 63;
    const int quad = lane >> 4, r = lane & 15;
    const int row0 = blockIdx.x * 64 + (wave >> 1) * 32;
    const int col0 = blockIdx.y * 64 + (wave & 1) * 32;

    v4f acc[2][2] = {};

    for (int kk = 0; kk < 512; kk += 32) {
        v8bf a0 = *(const v8bf*)(x + (size_t)(row0 +      r) * 512 + kk + quad * 8);
        v8bf a1 = *(const v8bf*)(x + (size_t)(row0 + 16 + r) * 512 + kk + quad * 8);
        v8bf b0 = load8f_bf(W + (size_t)(col0 +      r) * 512 + kk + quad * 8);
        v8bf b1 = load8f_bf(W + (size_t)(col0 + 16 + r) * 512 + kk + quad * 8);
        acc[0][0] = MFMA16(a0, b0, acc[0][0]);
        acc[0][1] = MFMA16(a0, b1, acc[0][1]);
        acc[1][0] = MFMA16(a1, b0, acc[1][0]);
        acc[1][1] = MFMA16(a1, b1, acc[1][1]);
    }

    for (int ni = 0; ni < 2; ni++) {
        const int n = col0 + ni * 16 + r;
        const float bv_ = bias[n];
        for (int mi = 0; mi < 2; mi++) {
            for (int i = 0; i < 4; i++) {
                const int m = row0 + mi * 16 + quad * 4 + i;
                y[(size_t)m * 512 + n] = acc[mi][ni][i] + bv_;
            }
        }
    }
}

// ---------------------------------------------------------------------------
extern "C" void kernel_launch(void* const* d_in, const int* in_sizes, int n_in,
                              void* d_out, int out_size, void* d_ws, size_t ws_size,
                              hipStream_t stream)
{
    const float* q    = (const float*)d_in[0];
    const float* k    = (const float*)d_in[1];
    const float* v    = (const float*)d_in[2];
    const int*   mask = (const int*)d_in[3];
    const float* Wq   = (const float*)d_in[4];
    const float* Wk   = (const float*)d_in[5];
    const float* Wv   = (const float*)d_in[6];
    const float* Wo   = (const float*)d_in[7];
    const float* bq   = (const float*)d_in[8];
    const float* bk   = (const float*)d_in[9];
    const float* bv   = (const float*)d_in[10];
    const float* bo   = (const float*)d_in[11];

    // ws layout (bf16 elems): Q[4M] K[4M] VT[4M] AO[4M] -> 32 MB total
    __bf16* ws  = (__bf16*)d_ws;
    __bf16* Qw  = ws;
    __bf16* Kw  = ws + 4194304;
    __bf16* VTw = ws + 8388608;
    __bf16* AOw = ws + 12582912;

    qkv_gemm<<<dim3(128, 8, 3), 256, 0, stream>>>(q, k, v, Wq, Wk, Wv, bq, bk, bv, Qw, Kw, VTw);
    attn<<<dim3(32, 32), 256, 0, stream>>>(Qw, Kw, VTw, mask, AOw);
    out_gemm<<<dim3(128, 8), 256, 0, stream>>>(AOw, Wo, bo, (float*)d_out);
}

// Round 3
// 314.488 us; speedup vs baseline: 2.0187x; 2.0187x over previous
//
#include <hip/hip_runtime.h>
#include <hip/hip_bf16.h>

// MHA layer. B=4, S=2048, HID=512, H=8, HD=64. fp32 in/out, bf16 MFMA inside.
// R3: attn restructured -> shared LDS K/V tiles (fragment-major, conflict-free),
// register-prefetch pipeline, operand-swapped S^T softmax (in-reg reductions),
// W pre-converted to bf16, GEMM wave tiles widened to 32x64.

typedef __bf16 v8bf __attribute__((ext_vector_type(8)));
typedef __bf16 v4bf __attribute__((ext_vector_type(4)));
typedef float  v4f  __attribute__((ext_vector_type(4)));

#define MFMA16(a, b, c) __builtin_amdgcn_mfma_f32_16x16x32_bf16((a), (b), (c), 0, 0, 0)

__device__ inline v8bf load8f_bf(const float* __restrict__ p) {
    const v4f a = *(const v4f*)p;
    const v4f b = *(const v4f*)(p + 4);
    v8bf r;
    r[0] = (__bf16)a[0]; r[1] = (__bf16)a[1]; r[2] = (__bf16)a[2]; r[3] = (__bf16)a[3];
    r[4] = (__bf16)b[0]; r[5] = (__bf16)b[1]; r[6] = (__bf16)b[2]; r[7] = (__bf16)b[3];
    return r;
}

// ---------------------------------------------------------------------------
// K0: convert Wq,Wk,Wv,Wo (each 512x512 fp32) -> bf16, concatenated.
// ---------------------------------------------------------------------------
__global__ __launch_bounds__(256) void cvt_w(
    const float* __restrict__ Wq, const float* __restrict__ Wk,
    const float* __restrict__ Wv, const float* __restrict__ Wo,
    __bf16* __restrict__ out)
{
    const int idx = (blockIdx.x * 256 + threadIdx.x) * 4;   // 1M elems total
    const int w = idx >> 18, off = idx & 262143;
    const float* src = (w == 0) ? Wq : (w == 1) ? Wk : (w == 2) ? Wv : Wo;
    const v4f x = *(const v4f*)(src + off);
    v4bf y;
    y[0] = (__bf16)x[0]; y[1] = (__bf16)x[1]; y[2] = (__bf16)x[2]; y[3] = (__bf16)x[3];
    *(v4bf*)(out + idx) = y;
}

// ---------------------------------------------------------------------------
// K1: QKV projection. grid (128, 4, 3), block 256. Wave tile 32x64 (2x4 MFMA).
// x fp32 (cvt on load), W bf16. Q,K -> [B,H,S,64]; V -> [B,H,64,S] (transposed).
// ---------------------------------------------------------------------------
__global__ __launch_bounds__(256) void qkv_gemm(
    const float* __restrict__ xq, const float* __restrict__ xk, const float* __restrict__ xv,
    const __bf16* __restrict__ Wb,
    const float* __restrict__ bq, const float* __restrict__ bk, const float* __restrict__ bv,
    __bf16* __restrict__ Qo, __bf16* __restrict__ Ko, __bf16* __restrict__ VTo)
{
    const int z = blockIdx.z;
    const float*  x    = (z == 0) ? xq : (z == 1) ? xk : xv;
    const __bf16* W    = Wb + (size_t)z * 262144;
    const float*  bias = (z == 0) ? bq : (z == 1) ? bk : bv;

    const int tid = threadIdx.x, wave = tid >> 6, lane = tid & 63;
    const int quad = lane >> 4, r = lane & 15;
    const int row0 = blockIdx.x * 64  + (wave >> 1) * 32;
    const int col0 = blockIdx.y * 128 + (wave & 1) * 64;

    v4f acc[2][4] = {};

    for (int kk = 0; kk < 512; kk += 32) {
        v8bf a0 = load8f_bf(x + (size_t)(row0 +      r) * 512 + kk + quad * 8);
        v8bf a1 = load8f_bf(x + (size_t)(row0 + 16 + r) * 512 + kk + quad * 8);
        v8bf b0 = *(const v8bf*)(W + (size_t)(col0 +      r) * 512 + kk + quad * 8);
        v8bf b1 = *(const v8bf*)(W + (size_t)(col0 + 16 + r) * 512 + kk + quad * 8);
        v8bf b2 = *(const v8bf*)(W + (size_t)(col0 + 32 + r) * 512 + kk + quad * 8);
        v8bf b3 = *(const v8bf*)(W + (size_t)(col0 + 48 + r) * 512 + kk + quad * 8);
        acc[0][0] = MFMA16(a0, b0, acc[0][0]); acc[0][1] = MFMA16(a0, b1, acc[0][1]);
        acc[0][2] = MFMA16(a0, b2, acc[0][2]); acc[0][3] = MFMA16(a0, b3, acc[0][3]);
        acc[1][0] = MFMA16(a1, b0, acc[1][0]); acc[1][1] = MFMA16(a1, b1, acc[1][1]);
        acc[1][2] = MFMA16(a1, b2, acc[1][2]); acc[1][3] = MFMA16(a1, b3, acc[1][3]);
    }

    for (int c = 0; c < 4; c++) {
        const int n = col0 + c * 16 + r;
        const float bv_ = bias[n];
        const int hh = n >> 6, hd = n & 63;
        for (int m = 0; m < 2; m++) {
            for (int i = 0; i < 4; i++) {
                const int mm = row0 + m * 16 + quad * 4 + i;
                const int bb = mm >> 11, s = mm & 2047;
                const float v = acc[m][c][i] + bv_;
                if (z == 2) {
                    VTo[((size_t)((bb * 8 + hh) * 64 + hd)) * 2048 + s] = (__bf16)v;
                } else {
                    __bf16* dst = (z == 0) ? Qo : Ko;
                    dst[((size_t)((bb * 8 + hh) * 2048 + s)) * 64 + hd] = (__bf16)v;
                }
            }
        }
    }
}

// ---------------------------------------------------------------------------
// K2: flash attention. grid (32, 32), block 256 (4 waves x 16 queries).
// Shared LDS K/V tile (16 KB, fragment-major), register-prefetch pipeline,
// S^T softmax (in-register reductions + 2 shfl).
// ---------------------------------------------------------------------------
__global__ __launch_bounds__(256) void attn(
    const __bf16* __restrict__ Q, const __bf16* __restrict__ K,
    const __bf16* __restrict__ VT, const int* __restrict__ mask,
    __bf16* __restrict__ AO)
{
    const int bh = blockIdx.y, b = bh >> 3, h = bh & 7;
    const int tid = threadIdx.x, wave = tid >> 6, lane = tid & 63;
    const int quad = lane >> 4, r = lane & 15;
    const int q0 = blockIdx.x * 64 + wave * 16;

    const __bf16* Qb = Q  + (size_t)bh * 2048 * 64;
    const __bf16* Kb = K  + (size_t)bh * 2048 * 64;
    const __bf16* Vb = VT + (size_t)bh * 64 * 2048;
    const int*    mb = mask + (size_t)b * 2048;

    // Fragment-major LDS: entry e holds 16B for lane (e&63) of segment (e>>6);
    // segment = (sub-tile t, hd-half h). Reads are lane-consecutive: 0 conflicts.
    __shared__ __align__(16) __bf16 Kls[4096];
    __shared__ __align__(16) __bf16 Vls[4096];
    __shared__ __align__(16) __bf16 Pls[4][16][72];  // +8 pad: 144B rows, 16B-aligned
    __shared__ float flagLS[2048];

    for (int i = tid; i < 2048; i += 256)
        flagLS[i] = (mb[i] != 0) ? 1.f : 0.f;

    // staging decode: this thread owns entries e1,e2 of both K and V tiles
    const int e1 = tid, e2 = tid + 256;
    int seg, l, t_, h_, rr, qd;
    seg = e1 >> 6; l = e1 & 63; t_ = seg >> 1; h_ = seg & 1; rr = l & 15; qd = l >> 4;
    const __bf16* kg1 = Kb + (size_t)(16 * t_ + rr) * 64   + h_ * 32 + qd * 8;
    const __bf16* vg1 = Vb + (size_t)(16 * t_ + rr) * 2048 + h_ * 32 + qd * 8;
    seg = e2 >> 6; l = e2 & 63; t_ = seg >> 1; h_ = seg & 1; rr = l & 15; qd = l >> 4;
    const __bf16* kg2 = Kb + (size_t)(16 * t_ + rr) * 64   + h_ * 32 + qd * 8;
    const __bf16* vg2 = Vb + (size_t)(16 * t_ + rr) * 2048 + h_ * 32 + qd * 8;

    // Q fragments resident (B-operand data == A-layout data)
    v8bf qf0 = *(const v8bf*)(Qb + (size_t)(q0 + r) * 64 +      quad * 8);
    v8bf qf1 = *(const v8bf*)(Qb + (size_t)(q0 + r) * 64 + 32 + quad * 8);

    float m_i = -1e30f, l_i = 0.f;   // for query q = r (this lane's S^T column)
    v4f o[4] = {};

    // prologue: tile 0 into registers
    v8bf ks1 = *(const v8bf*)kg1, ks2 = *(const v8bf*)kg2;
    v8bf vs1 = *(const v8bf*)vg1, vs2 = *(const v8bf*)vg2;

    for (int t = 0; t < 32; t++) {
        __syncthreads();                       // everyone done reading tile t-1
        ((v8bf*)Kls)[e1] = ks1; ((v8bf*)Kls)[e2] = ks2;
        ((v8bf*)Vls)[e1] = vs1; ((v8bf*)Vls)[e2] = vs2;
        if (t < 31) {                          // prefetch tile t+1 (wave-uniform branch)
            const int k0n = (t + 1) * 64;
            ks1 = *(const v8bf*)(kg1 + (size_t)k0n * 64);
            ks2 = *(const v8bf*)(kg2 + (size_t)k0n * 64);
            vs1 = *(const v8bf*)(vg1 + k0n);
            vs2 = *(const v8bf*)(vg2 + k0n);
        }
        __syncthreads();                       // tile t visible to all waves

        const int k0 = t * 64;
        // ---- S^T = K.Q^T : lane holds keys {16tt+quad*4+i} of query q=r
        v4f sa[4] = {};
        for (int tt = 0; tt < 4; tt++) {
            v8bf kf0 = ((const v8bf*)Kls)[(tt * 2 + 0) * 64 + lane];
            v8bf kf1 = ((const v8bf*)Kls)[(tt * 2 + 1) * 64 + lane];
            sa[tt] = MFMA16(kf0, qf0, sa[tt]);
            sa[tt] = MFMA16(kf1, qf1, sa[tt]);
        }
        // ---- scale + mask
        for (int tt = 0; tt < 4; tt++) {
            const v4f fl = *(const v4f*)&flagLS[k0 + tt * 16 + quad * 4];
            for (int i = 0; i < 4; i++) {
                const float s = sa[tt][i] * 0.125f;
                sa[tt][i] = (fl[i] != 0.f) ? s : -1e10f;
            }
        }
        // ---- online softmax: in-register tree + 2 cross-quad shuffles
        float mx = sa[0][0];
        for (int tt = 0; tt < 4; tt++)
            for (int i = 0; i < 4; i++) mx = fmaxf(mx, sa[tt][i]);
        mx = fmaxf(mx, __shfl_xor(mx, 16));
        mx = fmaxf(mx, __shfl_xor(mx, 32));
        const float mnew = fmaxf(m_i, mx);
        const float al = __expf(m_i - mnew);
        float sum = 0.f;
        float pv[16];
        for (int tt = 0; tt < 4; tt++)
            for (int i = 0; i < 4; i++) {
                const float p = __expf(sa[tt][i] - mnew);
                pv[tt * 4 + i] = p;
                sum += p;
            }
        sum += __shfl_xor(sum, 16);
        sum += __shfl_xor(sum, 32);
        l_i = l_i * al + sum;
        m_i = mnew;
        // alpha for this lane's O rows (q = quad*4+i) lives at lane quad*4+i
        float alr[4];
        for (int i = 0; i < 4; i++) alr[i] = __shfl(al, quad * 4 + i);
        for (int t2 = 0; t2 < 4; t2++)
            for (int i = 0; i < 4; i++) o[t2][i] *= alr[i];

        // ---- P: S^T C-layout -> A-layout via per-wave LDS (packed b64 writes)
        for (int tt = 0; tt < 4; tt++) {
            v4bf pk;
            pk[0] = (__bf16)pv[tt * 4 + 0]; pk[1] = (__bf16)pv[tt * 4 + 1];
            pk[2] = (__bf16)pv[tt * 4 + 2]; pk[3] = (__bf16)pv[tt * 4 + 3];
            *(v4bf*)&Pls[wave][r][tt * 16 + quad * 4] = pk;
        }
        asm volatile("s_waitcnt lgkmcnt(0)" ::: "memory");  // same-wave cross-lane
        v8bf pa0 = *(const v8bf*)&Pls[wave][r][     quad * 8];
        v8bf pa1 = *(const v8bf*)&Pls[wave][r][32 + quad * 8];

        // ---- O += P @ V (V fragments from shared LDS, conflict-free)
        for (int t2 = 0; t2 < 4; t2++) {
            v8bf vf0 = ((const v8bf*)Vls)[(t2 * 2 + 0) * 64 + lane];
            v8bf vf1 = ((const v8bf*)Vls)[(t2 * 2 + 1) * 64 + lane];
            o[t2] = MFMA16(pa0, vf0, o[t2]);
            o[t2] = MFMA16(pa1, vf1, o[t2]);
        }
    }

    // ---- epilogue: O rows are q = quad*4+i; l for that row lives at lane quad*4+i
    float lr[4];
    for (int i = 0; i < 4; i++) lr[i] = __shfl(l_i, quad * 4 + i);
    for (int t2 = 0; t2 < 4; t2++) {
        const int hd = t2 * 16 + r;
        for (int i = 0; i < 4; i++) {
            const int s = q0 + quad * 4 + i;
            AO[((size_t)b * 2048 + s) * 512 + h * 64 + hd] = (__bf16)(o[t2][i] / lr[i]);
        }
    }
}

// ---------------------------------------------------------------------------
// K3: output projection. grid (128, 4), block 256. Wave tile 32x64, all-bf16
// fragments, fp32 output.
// ---------------------------------------------------------------------------
__global__ __launch_bounds__(256) void out_gemm(
    const __bf16* __restrict__ x, const __bf16* __restrict__ W,
    const float* __restrict__ bias, float* __restrict__ y)
{
    const int tid = threadIdx.x, wave = tid >> 6, lane = tid & 63;
    const int quad = lane >> 4, r = lane & 15;
    const int row0 = blockIdx.x * 64  + (wave >> 1) * 32;
    const int col0 = blockIdx.y * 128 + (wave & 1) * 64;

    v4f acc[2][4] = {};

    for (int kk = 0; kk < 512; kk += 32) {
        v8bf a0 = *(const v8bf*)(x + (size_t)(row0 +      r) * 512 + kk + quad * 8);
        v8bf a1 = *(const v8bf*)(x + (size_t)(row0 + 16 + r) * 512 + kk + quad * 8);
        v8bf b0 = *(const v8bf*)(W + (size_t)(col0 +      r) * 512 + kk + quad * 8);
        v8bf b1 = *(const v8bf*)(W + (size_t)(col0 + 16 + r) * 512 + kk + quad * 8);
        v8bf b2 = *(const v8bf*)(W + (size_t)(col0 + 32 + r) * 512 + kk + quad * 8);
        v8bf b3 = *(const v8bf*)(W + (size_t)(col0 + 48 + r) * 512 + kk + quad * 8);
        acc[0][0] = MFMA16(a0, b0, acc[0][0]); acc[0][1] = MFMA16(a0, b1, acc[0][1]);
        acc[0][2] = MFMA16(a0, b2, acc[0][2]); acc[0][3] = MFMA16(a0, b3, acc[0][3]);
        acc[1][0] = MFMA16(a1, b0, acc[1][0]); acc[1][1] = MFMA16(a1, b1, acc[1][1]);
        acc[1][2] = MFMA16(a1, b2, acc[1][2]); acc[1][3] = MFMA16(a1, b3, acc[1][3]);
    }

    for (int c = 0; c < 4; c++) {
        const int n = col0 + c * 16 + r;
        const float bv_ = bias[n];
        for (int m = 0; m < 2; m++)
            for (int i = 0; i < 4; i++) {
                const int mm = row0 + m * 16 + quad * 4 + i;
                y[(size_t)mm * 512 + n] = acc[m][c][i] + bv_;
            }
    }
}

// ---------------------------------------------------------------------------
extern "C" void kernel_launch(void* const* d_in, const int* in_sizes, int n_in,
                              void* d_out, int out_size, void* d_ws, size_t ws_size,
                              hipStream_t stream)
{
    const float* q    = (const float*)d_in[0];
    const float* k    = (const float*)d_in[1];
    const float* v    = (const float*)d_in[2];
    const int*   mask = (const int*)d_in[3];
    const float* Wq   = (const float*)d_in[4];
    const float* Wk   = (const float*)d_in[5];
    const float* Wv   = (const float*)d_in[6];
    const float* Wo   = (const float*)d_in[7];
    const float* bq   = (const float*)d_in[8];
    const float* bk   = (const float*)d_in[9];
    const float* bv   = (const float*)d_in[10];
    const float* bo   = (const float*)d_in[11];

    // ws (bf16 elems): Q[4M] K[4M] VT[4M] AO[4M] Wb[1M] -> 35.7 MB
    __bf16* ws  = (__bf16*)d_ws;
    __bf16* Qw  = ws;
    __bf16* Kw  = ws + 4194304;
    __bf16* VTw = ws + 8388608;
    __bf16* AOw = ws + 12582912;
    __bf16* Wb  = ws + 16777216;

    cvt_w<<<dim3(1024), 256, 0, stream>>>(Wq, Wk, Wv, Wo, Wb);
    qkv_gemm<<<dim3(128, 4, 3), 256, 0, stream>>>(q, k, v, Wb, bq, bk, bv, Qw, Kw, VTw);
    attn<<<dim3(32, 32), 256, 0, stream>>>(Qw, Kw, VTw, mask, AOw);
    out_gemm<<<dim3(128, 4), 256, 0, stream>>>(AOw, Wb + 786432, bo, (float*)d_out);
}

// Round 4
// 250.465 us; speedup vs baseline: 2.5347x; 1.2556x over previous
//
#include <hip/hip_runtime.h>
#include <hip/hip_bf16.h>

// MHA layer. B=4, S=2048, HID=512, H=8, HD=64. fp32 in/out, bf16 MFMA inside.
// R4: qkv/out GEMMs rewritten as 128x128-tile LDS-staged kernels:
//   - fragment-major LDS (conflict-free b128), B via global_load_lds width=16,
//   - qkv A staged via register round-trip w/ fp32->bf16 cvt (no extra ws),
//   - out_gemm both operands via global_load_lds.
// attn unchanged from R3 (shared LDS K/V tiles + S^T softmax).

typedef __bf16 v8bf __attribute__((ext_vector_type(8)));
typedef __bf16 v4bf __attribute__((ext_vector_type(4)));
typedef float  v4f  __attribute__((ext_vector_type(4)));

#define MFMA16(a, b, c) __builtin_amdgcn_mfma_f32_16x16x32_bf16((a), (b), (c), 0, 0, 0)
#define GLDS16(g, l) __builtin_amdgcn_global_load_lds( \
    (const __attribute__((address_space(1))) void*)(g), \
    (__attribute__((address_space(3))) void*)(l), 16, 0, 0)

// ---------------------------------------------------------------------------
// K0: convert Wq,Wk,Wv,Wo (each 512x512 fp32) -> bf16, concatenated.
// ---------------------------------------------------------------------------
__global__ __launch_bounds__(256) void cvt_w(
    const float* __restrict__ Wq, const float* __restrict__ Wk,
    const float* __restrict__ Wv, const float* __restrict__ Wo,
    __bf16* __restrict__ out)
{
    const int idx = (blockIdx.x * 256 + threadIdx.x) * 4;   // 1M elems total
    const int w = idx >> 18, off = idx & 262143;
    const float* src = (w == 0) ? Wq : (w == 1) ? Wk : (w == 2) ? Wv : Wo;
    const v4f x = *(const v4f*)(src + off);
    v4bf y;
    y[0] = (__bf16)x[0]; y[1] = (__bf16)x[1]; y[2] = (__bf16)x[2]; y[3] = (__bf16)x[3];
    *(v4bf*)(out + idx) = y;
}

// ---------------------------------------------------------------------------
// K1: QKV projection. grid (64, 4, 3), block 256. Tile 128x128, BK=64.
// A = x fp32 (register-staged + cvt), B = W bf16 (global_load_lds).
// LDS fragment-major: entry e = 16B for lane (e&63) of segment (e>>6),
// segment = mtile*2 + kchunk. All LDS b128 ops lane-consecutive -> 0 conflicts.
// ---------------------------------------------------------------------------
__global__ __launch_bounds__(256) void qkv_gemm(
    const float* __restrict__ xq, const float* __restrict__ xk, const float* __restrict__ xv,
    const __bf16* __restrict__ Wb,
    const float* __restrict__ bq, const float* __restrict__ bk, const float* __restrict__ bv,
    __bf16* __restrict__ Qo, __bf16* __restrict__ Ko, __bf16* __restrict__ VTo)
{
    const int z = blockIdx.z;
    const float*  x    = (z == 0) ? xq : (z == 1) ? xk : xv;
    const __bf16* W    = Wb + (size_t)z * 262144;
    const float*  bias = (z == 0) ? bq : (z == 1) ? bk : bv;

    const int tid = threadIdx.x, wave = tid >> 6, lane = tid & 63;
    const int quad = lane >> 4, r = lane & 15;
    const int wm = wave >> 1, wn = wave & 1;
    const int row0 = blockIdx.x * 128, col0 = blockIdx.y * 128;

    __shared__ __align__(16) __bf16 As[8192];   // 16 KB, 16 segments
    __shared__ __align__(16) __bf16 Bs[8192];   // 16 KB, 16 segments

    // A staging: thread owns entries tid + 256*j, j=0..3
    const float* aptr[4];
    int adst[4];
    for (int j = 0; j < 4; j++) {
        const int e = tid + 256 * j;
        const int seg = e >> 6, ln = e & 63;
        const int mt = seg >> 1, kc = seg & 1, rr = ln & 15, qd = ln >> 4;
        aptr[j] = x + (size_t)(row0 + mt * 16 + rr) * 512 + kc * 32 + qd * 8;
        adst[j] = e * 8;
    }
    // B staging: wave stages segments wave*4+j via global_load_lds
    const __bf16* bptr[4];
    for (int j = 0; j < 4; j++) {
        const int seg = wave * 4 + j;
        bptr[j] = W + (size_t)(col0 + (seg >> 1) * 16 + r) * 512 + (seg & 1) * 32 + quad * 8;
    }

    v4f acc[4][4] = {};

    for (int kk = 0; kk < 512; kk += 64) {
        __syncthreads();                       // readers of prev tile done
        for (int j = 0; j < 4; j++)
            GLDS16(bptr[j] + kk, &Bs[(wave * 4 + j) * 512]);
        for (int j = 0; j < 4; j++) {
            const v4f f0 = *(const v4f*)(aptr[j] + kk);
            const v4f f1 = *(const v4f*)(aptr[j] + kk + 4);
            v8bf pk;
            pk[0] = (__bf16)f0[0]; pk[1] = (__bf16)f0[1];
            pk[2] = (__bf16)f0[2]; pk[3] = (__bf16)f0[3];
            pk[4] = (__bf16)f1[0]; pk[5] = (__bf16)f1[1];
            pk[6] = (__bf16)f1[2]; pk[7] = (__bf16)f1[3];
            *(v8bf*)&As[adst[j]] = pk;
        }
        __syncthreads();                       // tile visible

        for (int kc = 0; kc < 2; kc++) {
            v8bf a[4], b[4];
            for (int i = 0; i < 4; i++)
                a[i] = ((const v8bf*)As)[((wm * 4 + i) * 2 + kc) * 64 + lane];
            for (int i = 0; i < 4; i++)
                b[i] = ((const v8bf*)Bs)[((wn * 4 + i) * 2 + kc) * 64 + lane];
            for (int mi = 0; mi < 4; mi++)
                for (int ni = 0; ni < 4; ni++)
                    acc[mi][ni] = MFMA16(a[mi], b[ni], acc[mi][ni]);
        }
    }

    // epilogue: m = row0+wm*64+mi*16+quad*4+i, n = col0+wn*64+ni*16+r
    for (int ni = 0; ni < 4; ni++) {
        const int n = col0 + wn * 64 + ni * 16 + r;
        const float bv_ = bias[n];
        const int hh = n >> 6, hd = n & 63;
        for (int mi = 0; mi < 4; mi++) {
            const int mbase = row0 + wm * 64 + mi * 16 + quad * 4;
            const int bb = mbase >> 11, s0 = mbase & 2047;
            if (z == 2) {
                v4bf pk;
                for (int i = 0; i < 4; i++)
                    pk[i] = (__bf16)(acc[mi][ni][i] + bv_);
                *(v4bf*)&VTo[((size_t)((bb * 8 + hh) * 64 + hd)) * 2048 + s0] = pk;
            } else {
                __bf16* dst = (z == 0) ? Qo : Ko;
                for (int i = 0; i < 4; i++)
                    dst[((size_t)((bb * 8 + hh) * 2048 + s0 + i)) * 64 + hd] =
                        (__bf16)(acc[mi][ni][i] + bv_);
            }
        }
    }
}

// ---------------------------------------------------------------------------
// K2: flash attention (unchanged from R3). grid (32, 32), block 256.
// ---------------------------------------------------------------------------
__global__ __launch_bounds__(256) void attn(
    const __bf16* __restrict__ Q, const __bf16* __restrict__ K,
    const __bf16* __restrict__ VT, const int* __restrict__ mask,
    __bf16* __restrict__ AO)
{
    const int bh = blockIdx.y, b = bh >> 3, h = bh & 7;
    const int tid = threadIdx.x, wave = tid >> 6, lane = tid & 63;
    const int quad = lane >> 4, r = lane & 15;
    const int q0 = blockIdx.x * 64 + wave * 16;

    const __bf16* Qb = Q  + (size_t)bh * 2048 * 64;
    const __bf16* Kb = K  + (size_t)bh * 2048 * 64;
    const __bf16* Vb = VT + (size_t)bh * 64 * 2048;
    const int*    mb = mask + (size_t)b * 2048;

    __shared__ __align__(16) __bf16 Kls[4096];
    __shared__ __align__(16) __bf16 Vls[4096];
    __shared__ __align__(16) __bf16 Pls[4][16][72];
    __shared__ float flagLS[2048];

    for (int i = tid; i < 2048; i += 256)
        flagLS[i] = (mb[i] != 0) ? 1.f : 0.f;

    const int e1 = tid, e2 = tid + 256;
    int seg, l, t_, h_, rr, qd;
    seg = e1 >> 6; l = e1 & 63; t_ = seg >> 1; h_ = seg & 1; rr = l & 15; qd = l >> 4;
    const __bf16* kg1 = Kb + (size_t)(16 * t_ + rr) * 64   + h_ * 32 + qd * 8;
    const __bf16* vg1 = Vb + (size_t)(16 * t_ + rr) * 2048 + h_ * 32 + qd * 8;
    seg = e2 >> 6; l = e2 & 63; t_ = seg >> 1; h_ = seg & 1; rr = l & 15; qd = l >> 4;
    const __bf16* kg2 = Kb + (size_t)(16 * t_ + rr) * 64   + h_ * 32 + qd * 8;
    const __bf16* vg2 = Vb + (size_t)(16 * t_ + rr) * 2048 + h_ * 32 + qd * 8;

    v8bf qf0 = *(const v8bf*)(Qb + (size_t)(q0 + r) * 64 +      quad * 8);
    v8bf qf1 = *(const v8bf*)(Qb + (size_t)(q0 + r) * 64 + 32 + quad * 8);

    float m_i = -1e30f, l_i = 0.f;
    v4f o[4] = {};

    v8bf ks1 = *(const v8bf*)kg1, ks2 = *(const v8bf*)kg2;
    v8bf vs1 = *(const v8bf*)vg1, vs2 = *(const v8bf*)vg2;

    for (int t = 0; t < 32; t++) {
        __syncthreads();
        ((v8bf*)Kls)[e1] = ks1; ((v8bf*)Kls)[e2] = ks2;
        ((v8bf*)Vls)[e1] = vs1; ((v8bf*)Vls)[e2] = vs2;
        if (t < 31) {
            const int k0n = (t + 1) * 64;
            ks1 = *(const v8bf*)(kg1 + (size_t)k0n * 64);
            ks2 = *(const v8bf*)(kg2 + (size_t)k0n * 64);
            vs1 = *(const v8bf*)(vg1 + k0n);
            vs2 = *(const v8bf*)(vg2 + k0n);
        }
        __syncthreads();

        const int k0 = t * 64;
        v4f sa[4] = {};
        for (int tt = 0; tt < 4; tt++) {
            v8bf kf0 = ((const v8bf*)Kls)[(tt * 2 + 0) * 64 + lane];
            v8bf kf1 = ((const v8bf*)Kls)[(tt * 2 + 1) * 64 + lane];
            sa[tt] = MFMA16(kf0, qf0, sa[tt]);
            sa[tt] = MFMA16(kf1, qf1, sa[tt]);
        }
        for (int tt = 0; tt < 4; tt++) {
            const v4f fl = *(const v4f*)&flagLS[k0 + tt * 16 + quad * 4];
            for (int i = 0; i < 4; i++) {
                const float s = sa[tt][i] * 0.125f;
                sa[tt][i] = (fl[i] != 0.f) ? s : -1e10f;
            }
        }
        float mx = sa[0][0];
        for (int tt = 0; tt < 4; tt++)
            for (int i = 0; i < 4; i++) mx = fmaxf(mx, sa[tt][i]);
        mx = fmaxf(mx, __shfl_xor(mx, 16));
        mx = fmaxf(mx, __shfl_xor(mx, 32));
        const float mnew = fmaxf(m_i, mx);
        const float al = __expf(m_i - mnew);
        float sum = 0.f;
        float pv[16];
        for (int tt = 0; tt < 4; tt++)
            for (int i = 0; i < 4; i++) {
                const float p = __expf(sa[tt][i] - mnew);
                pv[tt * 4 + i] = p;
                sum += p;
            }
        sum += __shfl_xor(sum, 16);
        sum += __shfl_xor(sum, 32);
        l_i = l_i * al + sum;
        m_i = mnew;
        float alr[4];
        for (int i = 0; i < 4; i++) alr[i] = __shfl(al, quad * 4 + i);
        for (int t2 = 0; t2 < 4; t2++)
            for (int i = 0; i < 4; i++) o[t2][i] *= alr[i];

        for (int tt = 0; tt < 4; tt++) {
            v4bf pk;
            pk[0] = (__bf16)pv[tt * 4 + 0]; pk[1] = (__bf16)pv[tt * 4 + 1];
            pk[2] = (__bf16)pv[tt * 4 + 2]; pk[3] = (__bf16)pv[tt * 4 + 3];
            *(v4bf*)&Pls[wave][r][tt * 16 + quad * 4] = pk;
        }
        asm volatile("s_waitcnt lgkmcnt(0)" ::: "memory");
        v8bf pa0 = *(const v8bf*)&Pls[wave][r][     quad * 8];
        v8bf pa1 = *(const v8bf*)&Pls[wave][r][32 + quad * 8];

        for (int t2 = 0; t2 < 4; t2++) {
            v8bf vf0 = ((const v8bf*)Vls)[(t2 * 2 + 0) * 64 + lane];
            v8bf vf1 = ((const v8bf*)Vls)[(t2 * 2 + 1) * 64 + lane];
            o[t2] = MFMA16(pa0, vf0, o[t2]);
            o[t2] = MFMA16(pa1, vf1, o[t2]);
        }
    }

    float lr[4];
    for (int i = 0; i < 4; i++) lr[i] = __shfl(l_i, quad * 4 + i);
    for (int t2 = 0; t2 < 4; t2++) {
        const int hd = t2 * 16 + r;
        for (int i = 0; i < 4; i++) {
            const int s = q0 + quad * 4 + i;
            AO[((size_t)b * 2048 + s) * 512 + h * 64 + hd] = (__bf16)(o[t2][i] / lr[i]);
        }
    }
}

// ---------------------------------------------------------------------------
// K3: output projection. grid (64, 4), block 256. Tile 128x128, BK=64.
// Both operands bf16 via global_load_lds. fp32 output + bias.
// ---------------------------------------------------------------------------
__global__ __launch_bounds__(256) void out_gemm(
    const __bf16* __restrict__ Ai, const __bf16* __restrict__ W,
    const float* __restrict__ bias, float* __restrict__ y)
{
    const int tid = threadIdx.x, wave = tid >> 6, lane = tid & 63;
    const int quad = lane >> 4, r = lane & 15;
    const int wm = wave >> 1, wn = wave & 1;
    const int row0 = blockIdx.x * 128, col0 = blockIdx.y * 128;

    __shared__ __align__(16) __bf16 As[8192];
    __shared__ __align__(16) __bf16 Bs[8192];

    const __bf16* aptr[4];
    const __bf16* bptr[4];
    for (int j = 0; j < 4; j++) {
        const int seg = wave * 4 + j;
        const int mt = seg >> 1, kc = seg & 1;
        aptr[j] = Ai + (size_t)(row0 + mt * 16 + r) * 512 + kc * 32 + quad * 8;
        bptr[j] = W  + (size_t)(col0 + mt * 16 + r) * 512 + kc * 32 + quad * 8;
    }

    v4f acc[4][4] = {};

    for (int kk = 0; kk < 512; kk += 64) {
        __syncthreads();
        for (int j = 0; j < 4; j++) {
            GLDS16(aptr[j] + kk, &As[(wave * 4 + j) * 512]);
            GLDS16(bptr[j] + kk, &Bs[(wave * 4 + j) * 512]);
        }
        __syncthreads();

        for (int kc = 0; kc < 2; kc++) {
            v8bf a[4], b[4];
            for (int i = 0; i < 4; i++)
                a[i] = ((const v8bf*)As)[((wm * 4 + i) * 2 + kc) * 64 + lane];
            for (int i = 0; i < 4; i++)
                b[i] = ((const v8bf*)Bs)[((wn * 4 + i) * 2 + kc) * 64 + lane];
            for (int mi = 0; mi < 4; mi++)
                for (int ni = 0; ni < 4; ni++)
                    acc[mi][ni] = MFMA16(a[mi], b[ni], acc[mi][ni]);
        }
    }

    for (int ni = 0; ni < 4; ni++) {
        const int n = col0 + wn * 64 + ni * 16 + r;
        const float bv_ = bias[n];
        for (int mi = 0; mi < 4; mi++) {
            const int mbase = row0 + wm * 64 + mi * 16 + quad * 4;
            for (int i = 0; i < 4; i++)
                y[(size_t)(mbase + i) * 512 + n] = acc[mi][ni][i] + bv_;
        }
    }
}

// ---------------------------------------------------------------------------
extern "C" void kernel_launch(void* const* d_in, const int* in_sizes, int n_in,
                              void* d_out, int out_size, void* d_ws, size_t ws_size,
                              hipStream_t stream)
{
    const float* q    = (const float*)d_in[0];
    const float* k    = (const float*)d_in[1];
    const float* v    = (const float*)d_in[2];
    const int*   mask = (const int*)d_in[3];
    const float* Wq   = (const float*)d_in[4];
    const float* Wk   = (const float*)d_in[5];
    const float* Wv   = (const float*)d_in[6];
    const float* Wo   = (const float*)d_in[7];
    const float* bq   = (const float*)d_in[8];
    const float* bk   = (const float*)d_in[9];
    const float* bv   = (const float*)d_in[10];
    const float* bo   = (const float*)d_in[11];

    // ws (bf16 elems): Q[4M] K[4M] VT[4M] AO[4M] Wb[1M] -> 35.7 MB
    __bf16* ws  = (__bf16*)d_ws;
    __bf16* Qw  = ws;
    __bf16* Kw  = ws + 4194304;
    __bf16* VTw = ws + 8388608;
    __bf16* AOw = ws + 12582912;
    __bf16* Wb  = ws + 16777216;

    cvt_w<<<dim3(1024), 256, 0, stream>>>(Wq, Wk, Wv, Wo, Wb);
    qkv_gemm<<<dim3(64, 4, 3), 256, 0, stream>>>(q, k, v, Wb, bq, bk, bv, Qw, Kw, VTw);
    attn<<<dim3(32, 32), 256, 0, stream>>>(Qw, Kw, VTw, mask, AOw);
    out_gemm<<<dim3(64, 4), 256, 0, stream>>>(AOw, Wb + 786432, bo, (float*)d_out);
}